// Round 8
// baseline (496.822 us; speedup 1.0000x reference)
//
#include <hip/hip_runtime.h>

#define N_EDGES 160000
#define C_EMB 32
#define N_RBF 32

typedef float floatx4 __attribute__((ext_vector_type(4)));

#define PI_F 3.14159265358979323f
#define RSZ ((size_t)N_EDGES * 288)

// ======================= probe1: register-fed, 3-stream =======================
// No loads, no LDS. Mimics R1-P3's store pattern exactly: per block, 1152 fl4
// per stream x 3 streams. If THIS is slow -> address pattern (H3).
#define P1_BLOCKS 2000
__global__ __launch_bounds__(256) void probe1_regfed(float* __restrict__ ws) {
    const int tid = threadIdx.x, b = blockIdx.x;
    const size_t third = (size_t)P1_BLOCKS * 4608;
    float* s0 = ws + (size_t)b * 4608;
    for (int q = tid; q < 1152; q += 256) {
        floatx4 v;
        #pragma unroll
        for (int u = 0; u < 4; ++u) v[u] = (float)(q * 4 + u) + (float)tid;
        *(floatx4*)(s0 + 0 * third + 4 * q) = v;
        *(floatx4*)(s0 + 1 * third + 4 * q) = v * 2.0f;
        *(floatx4*)(s0 + 2 * third + 4 * q) = v * 3.0f;
    }
}

// ========================= probe2: LDS-fed, 3-stream ==========================
// Values come from ds_read chains (24 scalar LDS reads/iter like R1-P3), but
// zero global loads. If slow while probe1 fast -> H2 (LDS-fed store issue).
#define P2_BLOCKS 5000
__global__ __launch_bounds__(256) void probe2_ldsfed(float* __restrict__ ws) {
    __shared__ float s[1024];
    const int tid = threadIdx.x, b = blockIdx.x;
    #pragma unroll
    for (int k = 0; k < 4; ++k) s[tid * 4 + k] = (float)(tid + k) * 0.25f;
    __syncthreads();
    const size_t third = (size_t)P2_BLOCKS * 4608;
    float* s0 = ws + (size_t)b * 4608;
    for (int q = tid; q < 1152; q += 256) {
        floatx4 vI, vA, vS;
        #pragma unroll
        for (int u = 0; u < 4; ++u) {
            int f = q * 4 + u;
            int e = f / 288;
            int rem = f - e * 288;
            int cc = rem / 9;
            int p = rem - cc * 9;
            vI[u] = s[(e * 27 + p) & 1023]        * s[(cc * 9 + p) & 1023];
            vA[u] = s[(e * 27 + p + 256) & 1023]  * s[(cc * 9 + p + 512) & 1023];
            vS[u] = s[(e * 27 + p + 640) & 1023]  * s[(cc * 9 + p + 768) & 1023];
        }
        *(floatx4*)(s0 + 0 * third + 4 * q) = vI;
        *(floatx4*)(s0 + 1 * third + 4 * q) = vA;
        *(floatx4*)(s0 + 2 * third + 4 * q) = vS;
    }
}

// ================== probe3: global-load-fed, 3-stream (to out) ================
// One small L2-resident global load per iteration, consumed by the stores.
// Writes garbage over d_out (overwritten by the real kernel afterwards).
// If slow while probe1/2 fast -> H1 (vmcnt load->store serialization).
#define P3_BLOCKS 10000
__global__ __launch_bounds__(256) void probe3_loadfed(
    const float* __restrict__ src,   // ev: 480000 floats, L2-resident
    float* __restrict__ out) {
    const int tid = threadIdx.x, b = blockIdx.x;
    float* s0 = out + (size_t)b * 4608;
    for (int q = tid; q < 1152; q += 256) {
        float g = src[(b * 577 + q * 131 + tid) % 480000];  // varies per iter
        floatx4 v;
        #pragma unroll
        for (int u = 0; u < 4; ++u) v[u] = g + (float)(q * 4 + u);
        *(floatx4*)(s0 + 0 * RSZ + 4 * q) = v;
        *(floatx4*)(s0 + 1 * RSZ + 4 * q) = v * 2.0f;
        *(floatx4*)(s0 + 2 * RSZ + 4 * q) = v * 3.0f;
    }
}

// ===================== Real kernel: proven R1 single kernel ===================
#define EPBF 16
#define TF 256

__global__ __launch_bounds__(TF) void edge_embed_fallback(
    const int* __restrict__ atomic_numbers,
    const int* __restrict__ nbr,
    const float* __restrict__ ev,
    const float* __restrict__ z_table,
    const float* __restrict__ z_map_W,
    const float* __restrict__ dense_W,
    const float* __restrict__ dense_b,
    const float* __restrict__ rbf_beta,
    const float* __restrict__ rbf_centres,
    float* __restrict__ out)
{
    __shared__ float s_hi[EPBF][C_EMB];
    __shared__ float s_hj[EPBF][C_EMB];
    __shared__ float s_rbf[EPBF][N_RBF];
    __shared__ float s_hz[EPBF][C_EMB];
    __shared__ float s_c[EPBF][96];
    __shared__ float s_basis[EPBF][28];

    const int tid = threadIdx.x;
    const int e0 = blockIdx.x * EPBF;

    for (int idx = tid; idx < EPBF * C_EMB; idx += TF) {
        int e = idx >> 5, k = idx & 31, ge = e0 + e;
        s_hi[e][k] = z_table[atomic_numbers[nbr[ge]] * C_EMB + k];
        s_hj[e][k] = z_table[atomic_numbers[nbr[N_EDGES + ge]] * C_EMB + k];
    }
    for (int idx = tid; idx < EPBF * N_RBF; idx += TF) {
        int e = idx >> 5, n = idx & 31, ge = e0 + e;
        float x = ev[ge * 3 + 0], y = ev[ge * 3 + 1], z = ev[ge * 3 + 2];
        float r = sqrtf(x * x + y * y + z * z);
        float d = __expf(-r) - rbf_centres[n];
        s_rbf[e][n] = __expf(-rbf_beta[n] * d * d);
        if (n == 0)
            s_basis[e][27] = (r < 5.0f) ? 0.5f * (__cosf(PI_F * r * 0.2f) + 1.0f) : 0.0f;
    }
    for (int idx = tid; idx < EPBF * 27; idx += TF) {
        int e = idx / 27, t = idx - e * 27, ge = e0 + e;
        float x = ev[ge * 3 + 0], y = ev[ge * 3 + 1], z = ev[ge * 3 + 2];
        float rinv = rsqrtf(x * x + y * y + z * z);
        float vx = x * rinv, vy = y * rinv, vz = z * rinv;
        float val;
        if (t < 9) val = (t == 0 || t == 4 || t == 8) ? 1.0f : 0.0f;
        else if (t < 18) {
            int p = t - 9;
            switch (p) {
                case 1: val = -vz; break;
                case 2: val =  vy; break;
                case 3: val =  vz; break;
                case 5: val = -vx; break;
                case 6: val = -vy; break;
                case 7: val =  vx; break;
                default: val = 0.0f; break;
            }
        } else {
            int p = t - 18;
            int i = p / 3, j = p - 3 * i;
            float ri = (i == 0) ? vx : ((i == 1) ? vy : vz);
            float rj = (j == 0) ? vx : ((j == 1) ? vy : vz);
            val = ri * rj - ((i == j) ? (1.0f / 3.0f) : 0.0f);
        }
        s_basis[e][t] = val;
    }
    __syncthreads();
    for (int idx = tid; idx < EPBF * C_EMB; idx += TF) {
        int e = idx >> 5, cc = idx & 31;
        const float4* Wi  = (const float4*)(z_map_W + cc * 64);
        const float4* hi4 = (const float4*)s_hi[e];
        const float4* hj4 = (const float4*)s_hj[e];
        float acc = 0.0f;
        #pragma unroll
        for (int k = 0; k < 8; ++k) {
            float4 w = Wi[k]; float4 h = hi4[k];
            acc += w.x * h.x + w.y * h.y + w.z * h.z + w.w * h.w;
        }
        #pragma unroll
        for (int k = 0; k < 8; ++k) {
            float4 w = Wi[8 + k]; float4 h = hj4[k];
            acc += w.x * h.x + w.y * h.y + w.z * h.z + w.w * h.w;
        }
        s_hz[e][cc] = acc;
    }
    __syncthreads();
    for (int idx = tid; idx < EPBF * 96; idx += TF) {
        int e = idx / 96, m = idx - e * 96;
        int cc = m & 31;
        const float4* Wd  = (const float4*)(dense_W + m * 32);
        const float4* rb4 = (const float4*)s_rbf[e];
        float acc = dense_b[m];
        #pragma unroll
        for (int n = 0; n < 8; ++n) {
            float4 w = Wd[n]; float4 rv = rb4[n];
            acc += w.x * rv.x + w.y * rv.y + w.z * rv.z + w.w * rv.w;
        }
        s_c[e][m] = acc * s_basis[e][27] * s_hz[e][cc];
    }
    __syncthreads();
    float* outI = out + (size_t)e0 * 288;
    float* outA = out + RSZ + (size_t)e0 * 288;
    float* outS = out + 2 * RSZ + (size_t)e0 * 288;
    const int NQ = EPBF * 288 / 4;
    for (int q = tid; q < NQ; q += TF) {
        int fbase = q * 4;
        floatx4 aI, aA, aS;
        #pragma unroll
        for (int u = 0; u < 4; ++u) {
            int f = fbase + u;
            int e = f / 288;
            int rem = f - e * 288;
            int cc = rem / 9;
            int p = rem - cc * 9;
            aI[u] = s_c[e][cc]      * s_basis[e][p];
            aA[u] = s_c[e][32 + cc] * s_basis[e][9 + p];
            aS[u] = s_c[e][64 + cc] * s_basis[e][18 + p];
        }
        ((floatx4*)outI)[q] = aI;
        ((floatx4*)outA)[q] = aA;
        ((floatx4*)outS)[q] = aS;
    }
}

extern "C" void kernel_launch(void* const* d_in, const int* in_sizes, int n_in,
                              void* d_out, int out_size, void* d_ws, size_t ws_size,
                              hipStream_t stream) {
    const int*   an  = (const int*)d_in[0];
    const int*   nbr = (const int*)d_in[1];
    const float* ev  = (const float*)d_in[2];
    const float* zt  = (const float*)d_in[3];
    const float* zw  = (const float*)d_in[4];
    const float* dw  = (const float*)d_in[5];
    const float* db  = (const float*)d_in[6];
    const float* rb  = (const float*)d_in[7];
    const float* rc  = (const float*)d_in[8];
    float* outp = (float*)d_out;
    float* wsf  = (float*)d_ws;

    // probe3: garbage over d_out (rewritten below), isolates load->store vmcnt
    probe3_loadfed<<<dim3(P3_BLOCKS), 256, 0, stream>>>(ev, outp);

    // probe1: register-fed 3-stream to ws (110.6 MB)
    const size_t p1_f = (size_t)P1_BLOCKS * 4608 * 3;
    if (ws_size >= p1_f * sizeof(float))
        probe1_regfed<<<dim3(P1_BLOCKS), 256, 0, stream>>>(wsf);

    // probe2: LDS-fed 3-stream to ws (+276.5 MB)
    const size_t p2_f = (size_t)P2_BLOCKS * 4608 * 3;
    if (ws_size >= (p1_f + p2_f) * sizeof(float))
        probe2_ldsfed<<<dim3(P2_BLOCKS), 256, 0, stream>>>(wsf + p1_f);

    // real kernel (proven R1): overwrites all of d_out with correct values
    edge_embed_fallback<<<dim3(N_EDGES / EPBF), TF, 0, stream>>>(
        an, nbr, ev, zt, zw, dw, db, rb, rc, outp);
}

// Round 9
// 360.918 us; speedup vs baseline: 1.3766x; 1.3766x over previous
//
#include <hip/hip_runtime.h>

#define N_EDGES 160000
#define C_EMB 32
#define N_RBF 32
#define Z_MAX 119

typedef float floatx4 __attribute__((ext_vector_type(4)));

#define PI_F 3.14159265358979323f
#define RSZ ((size_t)N_EDGES * 288)

// =========================== k0: F/G pair tables ==============================
// F[z][cc] = zt[z]·zW[cc][0:32];  G[z][cc] = zt[z]·zW[cc][32:64]
__global__ __launch_bounds__(256) void k0_tables(
    const float* __restrict__ zt,   // (119, 32)
    const float* __restrict__ zw,   // (32, 64)
    float* __restrict__ FG)         // F=[0,3808), G=[3808,7616)
{
    int i = blockIdx.x * 256 + threadIdx.x;
    if (i >= 2 * Z_MAX * C_EMB) return;
    int which = i / (Z_MAX * C_EMB);
    int j = i - which * (Z_MAX * C_EMB);
    int z = j >> 5, cc = j & 31;
    const float* wrow = zw + cc * 64 + which * 32;
    const float* zrow = zt + z * 32;
    float acc = 0.0f;
    #pragma unroll
    for (int k = 0; k < 32; ++k) acc += zrow[k] * wrow[k];
    FG[i] = acc;
}

// ================= kA: features with per-edge hoisted scalars =================
// rec[e][0..95] = c (env & h_z folded), rec[e][96..122] = basis27
#define EPA 64
#define TA 256

__global__ __launch_bounds__(TA) void kA_features(
    const int* __restrict__ atomic_numbers,
    const int* __restrict__ nbr,
    const float* __restrict__ ev,
    const float* __restrict__ dense_W,     // (96, 32)
    const float* __restrict__ dense_b,     // (96,)
    const float* __restrict__ rbf_beta,
    const float* __restrict__ rbf_centres,
    const float* __restrict__ FG,
    float* __restrict__ rec)               // (N_EDGES, 128)
{
    __shared__ float s_er[EPA], s_env[EPA];
    __shared__ float s_vx[EPA], s_vy[EPA], s_vz[EPA];
    __shared__ int   s_zi[EPA], s_zj[EPA];
    __shared__ float s_rbf[EPA][N_RBF];

    const int tid = threadIdx.x;
    const int e0 = blockIdx.x * EPA;

    // phase 0: per-edge scalars computed ONCE (hoists 32x-redundant exp/rsqrt)
    if (tid < EPA) {
        int ge = e0 + tid;
        float x = ev[ge * 3 + 0], y = ev[ge * 3 + 1], z = ev[ge * 3 + 2];
        float r2 = x * x + y * y + z * z;
        float r = sqrtf(r2);
        float rinv = rsqrtf(r2);
        s_er[tid]  = __expf(-r);
        s_env[tid] = (r < 5.0f) ? 0.5f * (__cosf(PI_F * r * 0.2f) + 1.0f) : 0.0f;
        s_vx[tid] = x * rinv; s_vy[tid] = y * rinv; s_vz[tid] = z * rinv;
    } else if (tid < 2 * EPA) {
        s_zi[tid - EPA] = atomic_numbers[nbr[e0 + tid - EPA]];
    } else if (tid < 3 * EPA) {
        s_zj[tid - 2 * EPA] = atomic_numbers[nbr[N_EDGES + e0 + tid - 2 * EPA]];
    }
    __syncthreads();

    // phase 1a: rbf (reads only phase-0 LDS)
    for (int idx = tid; idx < EPA * N_RBF; idx += TA) {
        int e = idx >> 5, n = idx & 31;
        float d = s_er[e] - rbf_centres[n];
        s_rbf[e][n] = __expf(-rbf_beta[n] * d * d);
    }
    // phase 1b: basis -> rec directly
    for (int idx = tid; idx < EPA * 27; idx += TA) {
        int e = idx / 27, t = idx - e * 27, ge = e0 + e;
        float vx = s_vx[e], vy = s_vy[e], vz = s_vz[e];
        float val;
        if (t < 9) {
            val = (t == 0 || t == 4 || t == 8) ? 1.0f : 0.0f;
        } else if (t < 18) {
            int p = t - 9;
            switch (p) {
                case 1: val = -vz; break;
                case 2: val =  vy; break;
                case 3: val =  vz; break;
                case 5: val = -vx; break;
                case 6: val = -vy; break;
                case 7: val =  vx; break;
                default: val = 0.0f; break;
            }
        } else {
            int p = t - 18;
            int i = p / 3, j = p - 3 * i;
            float ri = (i == 0) ? vx : ((i == 1) ? vy : vz);
            float rj = (j == 0) ? vx : ((j == 1) ? vy : vz);
            val = ri * rj - ((i == j) ? (1.0f / 3.0f) : 0.0f);
        }
        rec[(size_t)ge * 128 + 96 + t] = val;
    }
    __syncthreads();

    // phase 2: c[m] = (b[m] + rbf·Wd[m]) * env * (F[zi][cc]+G[zj][cc])
    const float* Ft = FG;
    const float* Gt = FG + Z_MAX * C_EMB;
    for (int idx = tid; idx < EPA * 96; idx += TA) {
        int e = idx / 96, m = idx - e * 96, ge = e0 + e;
        int cc = m & 31;
        const float4* Wd  = (const float4*)(dense_W + m * 32);
        const float4* rb4 = (const float4*)s_rbf[e];
        float acc = dense_b[m];
        #pragma unroll
        for (int n = 0; n < 8; ++n) {
            float4 w = Wd[n]; float4 rv = rb4[n];
            acc += w.x * rv.x + w.y * rv.y + w.z * rv.z + w.w * rv.w;
        }
        float hz = Ft[s_zi[e] * 32 + cc] + Gt[s_zj[e] * 32 + cc];
        rec[(size_t)ge * 128 + m] = acc * s_env[e] * hz;
    }
}

// ================ kB: probe2-clone streaming expansion ========================
// Stage 16 edges' rec (8 KB) ONCE, one barrier, then the exact probe2 store
// loop shape: 3 streams x 1152 fl4, q += 256, fully coalesced.
#define KEPB 16
#define TB 256

__global__ __launch_bounds__(TB) void kB_stream(
    const float* __restrict__ rec,   // (N_EDGES, 128)
    float* __restrict__ out)
{
    __shared__ float s[KEPB * 128];  // 8 KB

    const int tid = threadIdx.x;
    const int e0 = blockIdx.x * KEPB;

    // stage: 512 fl4, contiguous, coalesced
    const floatx4* r4 = (const floatx4*)(rec + (size_t)e0 * 128);
    ((floatx4*)s)[tid]       = r4[tid];
    ((floatx4*)s)[tid + 256] = r4[tid + 256];
    __syncthreads();

    #pragma unroll
    for (int r = 0; r < 3; ++r) {
        float* ob = out + (size_t)r * RSZ + (size_t)e0 * 288;
        for (int q = tid; q < KEPB * 288 / 4; q += TB) {   // 1152
            int f = 4 * q;
            int e = f / 288;
            int rem = f - e * 288;
            int cc = rem / 9;
            int p = rem - cc * 9;
            const float* se = s + e * 128;
            floatx4 v;
            #pragma unroll
            for (int u = 0; u < 4; ++u) {
                int cross = (p + u >= 9);
                v[u] = se[32 * r + cc + cross] * se[96 + 9 * r + p + u - 9 * cross];
            }
            *(floatx4*)(ob + f) = v;
        }
    }
}

// ===================== Fallback: proven R1 single kernel ======================
#define EPBF 16
#define TF 256

__global__ __launch_bounds__(TF) void edge_embed_fallback(
    const int* __restrict__ atomic_numbers,
    const int* __restrict__ nbr,
    const float* __restrict__ ev,
    const float* __restrict__ z_table,
    const float* __restrict__ z_map_W,
    const float* __restrict__ dense_W,
    const float* __restrict__ dense_b,
    const float* __restrict__ rbf_beta,
    const float* __restrict__ rbf_centres,
    float* __restrict__ out)
{
    __shared__ float s_hi[EPBF][C_EMB];
    __shared__ float s_hj[EPBF][C_EMB];
    __shared__ float s_rbf[EPBF][N_RBF];
    __shared__ float s_hz[EPBF][C_EMB];
    __shared__ float s_c[EPBF][96];
    __shared__ float s_basis[EPBF][28];

    const int tid = threadIdx.x;
    const int e0 = blockIdx.x * EPBF;

    for (int idx = tid; idx < EPBF * C_EMB; idx += TF) {
        int e = idx >> 5, k = idx & 31, ge = e0 + e;
        s_hi[e][k] = z_table[atomic_numbers[nbr[ge]] * C_EMB + k];
        s_hj[e][k] = z_table[atomic_numbers[nbr[N_EDGES + ge]] * C_EMB + k];
    }
    for (int idx = tid; idx < EPBF * N_RBF; idx += TF) {
        int e = idx >> 5, n = idx & 31, ge = e0 + e;
        float x = ev[ge * 3 + 0], y = ev[ge * 3 + 1], z = ev[ge * 3 + 2];
        float r = sqrtf(x * x + y * y + z * z);
        float d = __expf(-r) - rbf_centres[n];
        s_rbf[e][n] = __expf(-rbf_beta[n] * d * d);
        if (n == 0)
            s_basis[e][27] = (r < 5.0f) ? 0.5f * (__cosf(PI_F * r * 0.2f) + 1.0f) : 0.0f;
    }
    for (int idx = tid; idx < EPBF * 27; idx += TF) {
        int e = idx / 27, t = idx - e * 27, ge = e0 + e;
        float x = ev[ge * 3 + 0], y = ev[ge * 3 + 1], z = ev[ge * 3 + 2];
        float rinv = rsqrtf(x * x + y * y + z * z);
        float vx = x * rinv, vy = y * rinv, vz = z * rinv;
        float val;
        if (t < 9) val = (t == 0 || t == 4 || t == 8) ? 1.0f : 0.0f;
        else if (t < 18) {
            int p = t - 9;
            switch (p) {
                case 1: val = -vz; break;
                case 2: val =  vy; break;
                case 3: val =  vz; break;
                case 5: val = -vx; break;
                case 6: val = -vy; break;
                case 7: val =  vx; break;
                default: val = 0.0f; break;
            }
        } else {
            int p = t - 18;
            int i = p / 3, j = p - 3 * i;
            float ri = (i == 0) ? vx : ((i == 1) ? vy : vz);
            float rj = (j == 0) ? vx : ((j == 1) ? vy : vz);
            val = ri * rj - ((i == j) ? (1.0f / 3.0f) : 0.0f);
        }
        s_basis[e][t] = val;
    }
    __syncthreads();
    for (int idx = tid; idx < EPBF * C_EMB; idx += TF) {
        int e = idx >> 5, cc = idx & 31;
        const float4* Wi  = (const float4*)(z_map_W + cc * 64);
        const float4* hi4 = (const float4*)s_hi[e];
        const float4* hj4 = (const float4*)s_hj[e];
        float acc = 0.0f;
        #pragma unroll
        for (int k = 0; k < 8; ++k) {
            float4 w = Wi[k]; float4 h = hi4[k];
            acc += w.x * h.x + w.y * h.y + w.z * h.z + w.w * h.w;
        }
        #pragma unroll
        for (int k = 0; k < 8; ++k) {
            float4 w = Wi[8 + k]; float4 h = hj4[k];
            acc += w.x * h.x + w.y * h.y + w.z * h.z + w.w * h.w;
        }
        s_hz[e][cc] = acc;
    }
    __syncthreads();
    for (int idx = tid; idx < EPBF * 96; idx += TF) {
        int e = idx / 96, m = idx - e * 96;
        int cc = m & 31;
        const float4* Wd  = (const float4*)(dense_W + m * 32);
        const float4* rb4 = (const float4*)s_rbf[e];
        float acc = dense_b[m];
        #pragma unroll
        for (int n = 0; n < 8; ++n) {
            float4 w = Wd[n]; float4 rv = rb4[n];
            acc += w.x * rv.x + w.y * rv.y + w.z * rv.z + w.w * rv.w;
        }
        s_c[e][m] = acc * s_basis[e][27] * s_hz[e][cc];
    }
    __syncthreads();
    float* outI = out + (size_t)e0 * 288;
    float* outA = out + RSZ + (size_t)e0 * 288;
    float* outS = out + 2 * RSZ + (size_t)e0 * 288;
    const int NQ = EPBF * 288 / 4;
    for (int q = tid; q < NQ; q += TF) {
        int fbase = q * 4;
        floatx4 aI, aA, aS;
        #pragma unroll
        for (int u = 0; u < 4; ++u) {
            int f = fbase + u;
            int e = f / 288;
            int rem = f - e * 288;
            int cc = rem / 9;
            int p = rem - cc * 9;
            aI[u] = s_c[e][cc]      * s_basis[e][p];
            aA[u] = s_c[e][32 + cc] * s_basis[e][9 + p];
            aS[u] = s_c[e][64 + cc] * s_basis[e][18 + p];
        }
        ((floatx4*)outI)[q] = aI;
        ((floatx4*)outA)[q] = aA;
        ((floatx4*)outS)[q] = aS;
    }
}

extern "C" void kernel_launch(void* const* d_in, const int* in_sizes, int n_in,
                              void* d_out, int out_size, void* d_ws, size_t ws_size,
                              hipStream_t stream) {
    const int*   an  = (const int*)d_in[0];
    const int*   nbr = (const int*)d_in[1];
    const float* ev  = (const float*)d_in[2];
    const float* zt  = (const float*)d_in[3];
    const float* zw  = (const float*)d_in[4];
    const float* dw  = (const float*)d_in[5];
    const float* db  = (const float*)d_in[6];
    const float* rb  = (const float*)d_in[7];
    const float* rc  = (const float*)d_in[8];
    float* outp = (float*)d_out;

    const size_t rec_f = (size_t)N_EDGES * 128;
    const size_t fg_f  = 2 * Z_MAX * C_EMB;
    const size_t need  = (rec_f + fg_f) * sizeof(float);   // ~82 MB

    if (ws_size >= need) {
        float* rec = (float*)d_ws;
        float* FG  = rec + rec_f;
        k0_tables<<<dim3((2 * Z_MAX * C_EMB + 255) / 256), 256, 0, stream>>>(zt, zw, FG);
        kA_features<<<dim3(N_EDGES / EPA), TA, 0, stream>>>(
            an, nbr, ev, dw, db, rb, rc, FG, rec);
        kB_stream<<<dim3(N_EDGES / KEPB), TB, 0, stream>>>(rec, outp);
    } else {
        edge_embed_fallback<<<dim3(N_EDGES / EPBF), TF, 0, stream>>>(
            an, nbr, ev, zt, zw, dw, db, rb, rc, outp);
    }
}